// Round 4
// baseline (1049.162 us; speedup 1.0000x reference)
//
#include <hip/hip_runtime.h>

#define LL 4096
#define NB 4
#define NC 64
#define NT 4
#define NLAYERS 10
#define XS 5120   // padded x row stride (in l units; x is [B][C][XS][4])
#define XPAD 512  // left/right zero pad (>= max dilation)

typedef float v2f __attribute__((ext_vector_type(2)));

// ---------------- Threefry-2x32, key = (0, 42), 20 rounds ----------------
__device__ __forceinline__ void threefry2x32(unsigned x0, unsigned x1,
                                             unsigned& o0, unsigned& o1) {
  const unsigned ks0 = 0u, ks1 = 42u;
  const unsigned ks2 = 0x1BD11BDAu ^ ks0 ^ ks1;
  const unsigned ks[3] = {ks0, ks1, ks2};
  const unsigned r0[4] = {13u, 15u, 26u, 6u};
  const unsigned r1[4] = {17u, 29u, 16u, 24u};
  x0 += ks0; x1 += ks1;
#pragma unroll
  for (int g = 0; g < 5; ++g) {
    const unsigned* rr = (g & 1) ? r1 : r0;
#pragma unroll
    for (int j = 0; j < 4; ++j) {
      x0 += x1;
      unsigned r = rr[j];
      x1 = (x1 << r) | (x1 >> (32u - r));
      x1 ^= x0;
    }
    x0 += ks[(g + 1) % 3];
    x1 += ks[(g + 2) % 3] + (unsigned)(g + 1);
  }
  o0 = x0; o1 = x1;
}

__device__ __forceinline__ float u01(unsigned bits) {
  return __uint_as_float((bits >> 9) | 0x3f800000u) - 1.0f;
}

// LIF step: v = v + (x - v)/1.2 ; spike = v>=0.5 ; v *= (1-spike)
__device__ __forceinline__ float lif_step(float& v, float xt) {
  v = v + (xt - v) / 1.2f;
  float s = (v >= 0.5f) ? 1.0f : 0.0f;
  v = v * (1.0f - s);
  return s;
}

// ---------------- prep: transpose skip/res 1x1 + build wT ----------------
// skipT/resT: [i][c'][c]. wT: [i][g16][ci][k][col8], col<4 gate co=g*4+col,
// col>=4 filt co=64+g*4+col-4.
__global__ void prep_kernel(const float* __restrict__ skip_w,
                            const float* __restrict__ res_w,
                            const float* __restrict__ conv_w,
                            float* __restrict__ skipT,
                            float* __restrict__ resT,
                            float* __restrict__ wT) {
  int i = blockIdx.x;
  for (int idx = threadIdx.x; idx < 4096; idx += 256) {
    int c = idx >> 6, cp = idx & 63;
    skipT[i * 4096 + cp * 64 + c] = skip_w[i * 4096 + c * 64 + cp];
    resT[i * 4096 + cp * 64 + c] = res_w[i * 4096 + c * 64 + cp];
  }
  for (int idx = threadIdx.x; idx < 16 * 64 * 3 * 8; idx += 256) {
    int col = idx & 7;
    int r = idx >> 3;
    int k = r % 3; r /= 3;
    int ci = r % 64;
    int g = r / 64;  // 0..15
    int co = (col < 4) ? (g * 4 + col) : (64 + g * 4 + (col - 4));
    wT[i * 24576 + idx] = conv_w[(i * 128 + co) * 192 + ci * 3 + k];
  }
}

// ---------------- diffusion-step embedding -> proj[i][b][c] ----------------
__global__ void proj_kernel(const int* __restrict__ dstep,
                            const float* __restrict__ w1, const float* __restrict__ b1,
                            const float* __restrict__ w2, const float* __restrict__ b2,
                            const float* __restrict__ pw, const float* __restrict__ pb,
                            float* __restrict__ proj) {
  __shared__ float e1[NB][NC];
  __shared__ float e2[NB][NC];
  int i = blockIdx.x;
  int tid = threadIdx.x;
  int b = tid >> 6, c = tid & 63;
  float d = (float)dstep[b];
  float v = d * w1[i * 64 + c] + b1[i * 64 + c];
  v = v / (1.0f + expf(-v));  // silu
  e1[b][c] = v;
  __syncthreads();
  float a = b2[i * 64 + c];
  for (int cp = 0; cp < 64; ++cp) a += e1[b][cp] * w2[(i * 64 + c) * 64 + cp];
  e2[b][c] = a;
  __syncthreads();
  float p = pb[i * 64 + c];
  for (int cp = 0; cp < 64; ++cp) p += e2[b][cp] * pw[(i * 64 + c) * 64 + cp];
  proj[(i * 4 + b) * 64 + c] = p;
}

// ---------------- per-(layer,b,co) proj-weighted tap sums S0,S1,S2 ----------------
__global__ void pc_kernel(const float* __restrict__ proj,
                          const float* __restrict__ conv_w,
                          float* __restrict__ pc) {
  __shared__ float pv[64];
  int layer = blockIdx.x, b = blockIdx.y;
  int tid = threadIdx.x;  // 128
  if (tid < 64) pv[tid] = proj[(layer * 4 + b) * 64 + tid];
  __syncthreads();
  int co = tid;
  const float* w = conv_w + (layer * 128 + co) * 192;
  float s0 = 0.0f, s1 = 0.0f, s2 = 0.0f;
  for (int ci = 0; ci < 64; ++ci) {
    float p = pv[ci];
    s0 += p * w[ci * 3 + 0];
    s1 += p * w[ci * 3 + 1];
    s2 += p * w[ci * 3 + 2];
  }
  float* o = pc + ((layer * 4 + b) * 128 + co) * 3;
  o[0] = s0; o[1] = s1; o[2] = s2;
}

// ---------------- zero the pad margins of BOTH x buffers ----------------
__global__ void padzero_kernel(float* __restrict__ x0, float* __restrict__ x1) {
  int row = blockIdx.x;  // 512 rows = 2 bufs x B*C
  float* base = (row < 256 ? x0 : x1) + (size_t)(row & 255) * XS * 4;
  for (int i = threadIdx.x; i < XPAD; i += 256) {
    *(float4*)&base[i * 4] = float4{0.f, 0.f, 0.f, 0.f};
    *(float4*)&base[(XPAD + LL + i) * 4] = float4{0.f, 0.f, 0.f, 0.f};
  }
}

// ---------------- Poisson encode + input conv + LIF -> x [B][C][XS][4] ---------
__global__ void encode_lif_kernel(const float* __restrict__ audio,
                                  const float* __restrict__ W_in,
                                  const float* __restrict__ b_in,
                                  float* __restrict__ x) {
  int tid = threadIdx.x;
  int lq = tid & 63, grp = tid >> 6;
  int l = blockIdx.x * 64 + lq;
  int b = blockIdx.y;
  float a = audio[b * LL + l];
  unsigned p0 = (unsigned)(b * LL + l);  // t=0 (o0), t=2 (o1)
  unsigned p1 = 16384u + p0;             // t=1 (o0), t=3 (o1)
  unsigned o00, o01, o10, o11;
  threefry2x32(p0, p0 + 32768u, o00, o01);
  threefry2x32(p1, p1 + 32768u, o10, o11);
  float sp[4];
  sp[0] = (u01(o00) < a) ? 1.0f : 0.0f;
  sp[1] = (u01(o10) < a) ? 1.0f : 0.0f;
  sp[2] = (u01(o01) < a) ? 1.0f : 0.0f;
  sp[3] = (u01(o11) < a) ? 1.0f : 0.0f;
  for (int j = 0; j < 16; ++j) {
    int c = grp * 16 + j;
    float w = W_in[c], bb = b_in[c];
    float v = 0.0f;
    float4 o;
    float* op = (float*)&o;
#pragma unroll
    for (int t = 0; t < 4; ++t) op[t] = lif_step(v, w * sp[t] + bb);
    *(float4*)&x[(size_t)((b * 64 + c) * XS + XPAD + l) * 4] = o;
  }
}

// ---------------- FUSED layer: dilated conv + LIF + gate -> y in LDS,
//                  then 1x1 skip/res from LDS. x ping-pong: reads xin
//                  (read-only this dispatch), writes xout = xin + res.
// grid (256, 4): l-tile 16, b. block 256.
// Phase A thread: (grp 0..15, lq 0..15): 1 l, 4 t, 4 gate + 4 filt co
//   -> gated y into y_lds[64co][17][4t] (l-padded: 4-way max on write,
//      2-way/broadcast on read).
// Phase B thread: (q=grp -> c0=q*4, lq): skip+res for 4 c over 64 cp from
//   y_lds; RMW tskip, xout = xin + res. cp ascending = old summation order.
// 1024 blocks = 4/CU = 16 waves/CU; FMA issue floor ~27us/layer vs 81us
// for the split kernels; y never touches HBM (saves 33 MB/layer).
template <int DIL>
__global__ __launch_bounds__(256, 4) void fused_layer_kernel(
    const float* __restrict__ xin, float* __restrict__ xout,
    const float* __restrict__ wT, const float* __restrict__ conv_b,
    const float* __restrict__ pc, const float* __restrict__ skipT,
    const float* __restrict__ resT, const float* __restrict__ skip_b,
    const float* __restrict__ res_b, float* __restrict__ tskip, int layer) {
  __shared__ float y_lds[64][17][4];  // [co][l(+pad)][t], 17 KB
  int tid = threadIdx.x;
  int lq = tid & 15;
  int grp = tid >> 4;  // 0..15
  int b = blockIdx.y;
  int l = blockIdx.x * 16 + lq;

  // ---- phase A: conv + LIF + gate ----
  {
    const float* wbase = wT + (size_t)(layer * 16 + grp) * 1536;
    const float* px = xin + (size_t)((b * 64) * XS + XPAD + l) * 4;  // ci=0

    v2f ag[8], af[8];  // [t4][pair2]
#pragma unroll
    for (int qq = 0; qq < 8; ++qq) {
      ag[qq] = (v2f)(0.0f);
      af[qq] = (v2f)(0.0f);
    }

    float4 xa[3], xb[3];  // [k] = 4 t values
    auto loadx = [&](float4* dst) {
      dst[0] = *(const float4*)(px - (size_t)DIL * 4);
      dst[1] = *(const float4*)px;
      dst[2] = *(const float4*)(px + (size_t)DIL * 4);
      px += (size_t)XS * 4;
    };
    auto compute = [&](int ci, const float4* xv) {
#pragma unroll
      for (int k = 0; k < 3; ++k) {
        float4 gq = *(const float4*)&wbase[(ci * 3 + k) * 8];
        float4 fq = *(const float4*)&wbase[(ci * 3 + k) * 8 + 4];
        v2f g0, g1, f0, f1;
        g0.x = gq.x; g0.y = gq.y; g1.x = gq.z; g1.y = gq.w;
        f0.x = fq.x; f0.y = fq.y; f1.x = fq.z; f1.y = fq.w;
        const float* xk = (const float*)&xv[k];
#pragma unroll
        for (int t = 0; t < 4; ++t) {
          float xq = xk[t];
          v2f x2;
          x2.x = xq; x2.y = xq;
          ag[t * 2 + 0] += g0 * x2;
          ag[t * 2 + 1] += g1 * x2;
          af[t * 2 + 0] += f0 * x2;
          af[t * 2 + 1] += f1 * x2;
        }
      }
    };

    loadx(xa);
    for (int ci = 0; ci < 64; ci += 2) {
      loadx(xb);
      compute(ci, xa);
      if (ci + 2 < 64) loadx(xa);
      compute(ci + 1, xb);
    }

    const float SIG1 = 0.73105857863000489f;   // sigmoid(1) fp32
    const float TANH1 = 0.76159415595576486f;  // tanh(1) fp32
    bool lb = (l < DIL), rb = (l >= LL - DIL);
#pragma unroll
    for (int j = 0; j < 4; ++j) {
      int cog = grp * 4 + j;
      int cof = 64 + grp * 4 + j;
      const float* pg = pc + ((layer * 4 + b) * 128 + cog) * 3;
      const float* pf = pc + ((layer * 4 + b) * 128 + cof) * 3;
      float S0g = pg[0], S1g = pg[1], S2g = pg[2];
      float S0f = pf[0], S1f = pf[1], S2f = pf[2];
      float bg = conv_b[layer * 128 + cog] + S0g + S1g + S2g;
      float bf = conv_b[layer * 128 + cof] + S0f + S1f + S2f;
      bg -= (lb ? S0g : 0.0f) + (rb ? S2g : 0.0f);
      bf -= (lb ? S0f : 0.0f) + (rb ? S2f : 0.0f);
      float vg = 0.0f, vf = 0.0f;
      float4 o;
      float* op = (float*)&o;
#pragma unroll
      for (int t = 0; t < 4; ++t) {
        float av = ag[t * 2 + (j >> 1)][j & 1];
        float fv = af[t * 2 + (j >> 1)][j & 1];
        float sg = lif_step(vg, av + bg);
        float sf = lif_step(vf, fv + bf);
        float gv = (sg != 0.0f) ? SIG1 : 0.5f;
        float tv = (sf != 0.0f) ? TANH1 : 0.0f;
        op[t] = gv * tv;
      }
      *(float4*)&y_lds[cog][lq][0] = o;
    }
  }

  __syncthreads();

  // ---- phase B: skip + res 1x1 from y_lds ----
  {
    int c0 = grp * 4;
    const float* sw = skipT + layer * 4096 + c0;  // [cp][c]
    const float* rw = resT + layer * 4096 + c0;

    v2f as[8], ar[8];  // [c4][t-pair2]
#pragma unroll
    for (int qq = 0; qq < 8; ++qq) {
      as[qq] = (v2f)(0.0f);
      ar[qq] = (v2f)(0.0f);
    }

    float4 wsa = *(const float4*)&sw[0];
    float4 wra = *(const float4*)&rw[0];
    for (int cp = 0; cp < 64; ++cp) {
      int cpn = (cp < 63) ? cp + 1 : 63;
      float4 wsb = *(const float4*)&sw[cpn * 64];
      float4 wrb = *(const float4*)&rw[cpn * 64];
      float4 yv = *(const float4*)&y_lds[cp][lq][0];
      v2f yp0, yp1;
      yp0.x = yv.x; yp0.y = yv.y;
      yp1.x = yv.z; yp1.y = yv.w;
      float wsv[4] = {wsa.x, wsa.y, wsa.z, wsa.w};
      float wrv[4] = {wra.x, wra.y, wra.z, wra.w};
#pragma unroll
      for (int i = 0; i < 4; ++i) {
        v2f w2s, w2r;
        w2s.x = wsv[i]; w2s.y = wsv[i];
        w2r.x = wrv[i]; w2r.y = wrv[i];
        as[i * 2 + 0] += w2s * yp0;
        as[i * 2 + 1] += w2s * yp1;
        ar[i * 2 + 0] += w2r * yp0;
        ar[i * 2 + 1] += w2r * yp1;
      }
      wsa = wsb; wra = wrb;
    }

#pragma unroll
    for (int i = 0; i < 4; ++i) {
      int c = c0 + i;
      float sb = skip_b[layer * 64 + c];
      float rbv = res_b[layer * 64 + c];
      // skip -> tskip RMW
      {
        size_t idx = (size_t)((b * 64 + c) * LL + l) * 4;
        float4 o0;
        if (layer == 0) {
          o0 = float4{0.f, 0.f, 0.f, 0.f};
        } else {
          o0 = *(const float4*)&tskip[idx];
        }
        o0.x += as[i * 2 + 0][0] + sb;
        o0.y += as[i * 2 + 0][1] + sb;
        o0.z += as[i * 2 + 1][0] + sb;
        o0.w += as[i * 2 + 1][1] + sb;
        *(float4*)&tskip[idx] = o0;
      }
      // res -> xout = xin + res
      {
        size_t idx = (size_t)((b * 64 + c) * XS + XPAD + l) * 4;
        float4 o0 = *(const float4*)&xin[idx];
        o0.x += ar[i * 2 + 0][0] + rbv;
        o0.y += ar[i * 2 + 0][1] + rbv;
        o0.z += ar[i * 2 + 1][0] + rbv;
        o0.w += ar[i * 2 + 1][1] + rbv;
        *(float4*)&xout[idx] = o0;
      }
    }
  }
}

// ---------------- output conv + LIF + sum over T ----------------
__global__ void out_kernel(const float* __restrict__ tskip,
                           const float* __restrict__ W_out,
                           const float* __restrict__ b_out,
                           float* __restrict__ out) {
  __shared__ float red[4][4][64];  // [grp][t][lq]
  int tid = threadIdx.x;
  int lq = tid & 63, grp = tid >> 6;
  int l = blockIdx.x * 64 + lq;
  int b = blockIdx.y;
  float acc[4] = {0.0f, 0.0f, 0.0f, 0.0f};
  for (int j = 0; j < 16; ++j) {
    int c = grp * 16 + j;
    float w = W_out[c];
    float4 sv = *(const float4*)&tskip[(size_t)((b * 64 + c) * LL + l) * 4];
    acc[0] += fmaxf(sv.x, 0.0f) * w;
    acc[1] += fmaxf(sv.y, 0.0f) * w;
    acc[2] += fmaxf(sv.z, 0.0f) * w;
    acc[3] += fmaxf(sv.w, 0.0f) * w;
  }
#pragma unroll
  for (int t = 0; t < 4; ++t) red[grp][t][lq] = acc[t];
  __syncthreads();
  if (grp == 0) {
    float bo = b_out[0];
    float v = 0.0f, s = 0.0f;
#pragma unroll
    for (int t = 0; t < 4; ++t) {
      float a = red[0][t][lq] + red[1][t][lq] + red[2][t][lq] + red[3][t][lq] + bo;
      s += lif_step(v, a);
    }
    out[b * LL + l] = s;
  }
}

extern "C" void kernel_launch(void* const* d_in, const int* in_sizes, int n_in,
                              void* d_out, int out_size, void* d_ws, size_t ws_size,
                              hipStream_t stream) {
  const float* audio   = (const float*)d_in[0];
  const int*   dstep   = (const int*)d_in[1];
  const float* W_in    = (const float*)d_in[2];
  const float* b_in    = (const float*)d_in[3];
  const float* demb_w1 = (const float*)d_in[4];
  const float* demb_b1 = (const float*)d_in[5];
  const float* demb_w2 = (const float*)d_in[6];
  const float* demb_b2 = (const float*)d_in[7];
  const float* dproj_w = (const float*)d_in[8];
  const float* dproj_b = (const float*)d_in[9];
  const float* conv_w  = (const float*)d_in[10];
  const float* conv_b  = (const float*)d_in[11];
  const float* skip_w  = (const float*)d_in[12];
  const float* skip_b  = (const float*)d_in[13];
  const float* res_w   = (const float*)d_in[14];
  const float* res_b   = (const float*)d_in[15];
  const float* W_out   = (const float*)d_in[16];
  const float* b_out   = (const float*)d_in[17];
  float* out = (float*)d_out;
  float* ws = (float*)d_ws;

  float* proj  = ws;                   // 2560
  float* skipT = proj + 2560;          // 40960
  float* resT  = skipT + 40960;        // 40960
  float* pc    = resT + 40960;         // 15360
  float* wT    = pc + 15360;           // 10*16*64*24 = 245760
  float* x0    = wT + 245760;          // 4*64*5120*4 = 5242880
  float* x1    = x0 + 5242880;         // 5242880
  float* tskip = x1 + 5242880;         // 4*64*4096*4 = 4194304
  // total: 15,025,664 floats = 60.1 MB

  prep_kernel<<<10, 256, 0, stream>>>(skip_w, res_w, conv_w, skipT, resT, wT);
  proj_kernel<<<10, 256, 0, stream>>>(dstep, demb_w1, demb_b1, demb_w2, demb_b2,
                                      dproj_w, dproj_b, proj);
  pc_kernel<<<dim3(10, 4), 128, 0, stream>>>(proj, conv_w, pc);
  padzero_kernel<<<512, 256, 0, stream>>>(x0, x1);
  encode_lif_kernel<<<dim3(64, 4), 256, 0, stream>>>(audio, W_in, b_in, x0);

  float* xcur = x0;
  float* xnxt = x1;
  for (int i = 0; i < NLAYERS; ++i) {
    dim3 gc(256, 4);
    switch (i) {
      case 0: fused_layer_kernel<1><<<gc, 256, 0, stream>>>(xcur, xnxt, wT, conv_b, pc, skipT, resT, skip_b, res_b, tskip, i); break;
      case 1: fused_layer_kernel<2><<<gc, 256, 0, stream>>>(xcur, xnxt, wT, conv_b, pc, skipT, resT, skip_b, res_b, tskip, i); break;
      case 2: fused_layer_kernel<4><<<gc, 256, 0, stream>>>(xcur, xnxt, wT, conv_b, pc, skipT, resT, skip_b, res_b, tskip, i); break;
      case 3: fused_layer_kernel<8><<<gc, 256, 0, stream>>>(xcur, xnxt, wT, conv_b, pc, skipT, resT, skip_b, res_b, tskip, i); break;
      case 4: fused_layer_kernel<16><<<gc, 256, 0, stream>>>(xcur, xnxt, wT, conv_b, pc, skipT, resT, skip_b, res_b, tskip, i); break;
      case 5: fused_layer_kernel<32><<<gc, 256, 0, stream>>>(xcur, xnxt, wT, conv_b, pc, skipT, resT, skip_b, res_b, tskip, i); break;
      case 6: fused_layer_kernel<64><<<gc, 256, 0, stream>>>(xcur, xnxt, wT, conv_b, pc, skipT, resT, skip_b, res_b, tskip, i); break;
      case 7: fused_layer_kernel<128><<<gc, 256, 0, stream>>>(xcur, xnxt, wT, conv_b, pc, skipT, resT, skip_b, res_b, tskip, i); break;
      case 8: fused_layer_kernel<256><<<gc, 256, 0, stream>>>(xcur, xnxt, wT, conv_b, pc, skipT, resT, skip_b, res_b, tskip, i); break;
      case 9: fused_layer_kernel<512><<<gc, 256, 0, stream>>>(xcur, xnxt, wT, conv_b, pc, skipT, resT, skip_b, res_b, tskip, i); break;
    }
    float* tmp = xcur; xcur = xnxt; xnxt = tmp;
  }
  out_kernel<<<dim3(64, 4), 256, 0, stream>>>(tskip, W_out, b_out, out);
}

// Round 5
// 891.049 us; speedup vs baseline: 1.1774x; 1.1774x over previous
//
#include <hip/hip_runtime.h>

#define LL 4096
#define NB 4
#define NC 64
#define NT 4
#define NLAYERS 10
#define XS 5120   // padded x row stride (in l units; x is [B][C][XS][4])
#define XPAD 512  // left/right zero pad (>= max dilation)

typedef float v2f __attribute__((ext_vector_type(2)));

// ---------------- Threefry-2x32, key = (0, 42), 20 rounds ----------------
__device__ __forceinline__ void threefry2x32(unsigned x0, unsigned x1,
                                             unsigned& o0, unsigned& o1) {
  const unsigned ks0 = 0u, ks1 = 42u;
  const unsigned ks2 = 0x1BD11BDAu ^ ks0 ^ ks1;
  const unsigned ks[3] = {ks0, ks1, ks2};
  const unsigned r0[4] = {13u, 15u, 26u, 6u};
  const unsigned r1[4] = {17u, 29u, 16u, 24u};
  x0 += ks0; x1 += ks1;
#pragma unroll
  for (int g = 0; g < 5; ++g) {
    const unsigned* rr = (g & 1) ? r1 : r0;
#pragma unroll
    for (int j = 0; j < 4; ++j) {
      x0 += x1;
      unsigned r = rr[j];
      x1 = (x1 << r) | (x1 >> (32u - r));
      x1 ^= x0;
    }
    x0 += ks[(g + 1) % 3];
    x1 += ks[(g + 2) % 3] + (unsigned)(g + 1);
  }
  o0 = x0; o1 = x1;
}

__device__ __forceinline__ float u01(unsigned bits) {
  return __uint_as_float((bits >> 9) | 0x3f800000u) - 1.0f;
}

// LIF step: v = v + (x - v)/1.2 ; spike = v>=0.5 ; v *= (1-spike)
__device__ __forceinline__ float lif_step(float& v, float xt) {
  v = v + (xt - v) / 1.2f;
  float s = (v >= 0.5f) ? 1.0f : 0.0f;
  v = v * (1.0f - s);
  return s;
}

// ---------------- prep: transpose skip/res 1x1 + build wT ----------------
// skipT/resT: [i][c'][c]. wT: [i][g16][ci][k][col8], col<4 gate co=g*4+col,
// col>=4 filt co=64+g*4+col-4.
__global__ void prep_kernel(const float* __restrict__ skip_w,
                            const float* __restrict__ res_w,
                            const float* __restrict__ conv_w,
                            float* __restrict__ skipT,
                            float* __restrict__ resT,
                            float* __restrict__ wT) {
  int i = blockIdx.x;
  for (int idx = threadIdx.x; idx < 4096; idx += 256) {
    int c = idx >> 6, cp = idx & 63;
    skipT[i * 4096 + cp * 64 + c] = skip_w[i * 4096 + c * 64 + cp];
    resT[i * 4096 + cp * 64 + c] = res_w[i * 4096 + c * 64 + cp];
  }
  for (int idx = threadIdx.x; idx < 16 * 64 * 3 * 8; idx += 256) {
    int col = idx & 7;
    int r = idx >> 3;
    int k = r % 3; r /= 3;
    int ci = r % 64;
    int g = r / 64;  // 0..15
    int co = (col < 4) ? (g * 4 + col) : (64 + g * 4 + (col - 4));
    wT[i * 24576 + idx] = conv_w[(i * 128 + co) * 192 + ci * 3 + k];
  }
}

// ---------------- diffusion-step embedding -> proj[i][b][c] ----------------
__global__ void proj_kernel(const int* __restrict__ dstep,
                            const float* __restrict__ w1, const float* __restrict__ b1,
                            const float* __restrict__ w2, const float* __restrict__ b2,
                            const float* __restrict__ pw, const float* __restrict__ pb,
                            float* __restrict__ proj) {
  __shared__ float e1[NB][NC];
  __shared__ float e2[NB][NC];
  int i = blockIdx.x;
  int tid = threadIdx.x;
  int b = tid >> 6, c = tid & 63;
  float d = (float)dstep[b];
  float v = d * w1[i * 64 + c] + b1[i * 64 + c];
  v = v / (1.0f + expf(-v));  // silu
  e1[b][c] = v;
  __syncthreads();
  float a = b2[i * 64 + c];
  for (int cp = 0; cp < 64; ++cp) a += e1[b][cp] * w2[(i * 64 + c) * 64 + cp];
  e2[b][c] = a;
  __syncthreads();
  float p = pb[i * 64 + c];
  for (int cp = 0; cp < 64; ++cp) p += e2[b][cp] * pw[(i * 64 + c) * 64 + cp];
  proj[(i * 4 + b) * 64 + c] = p;
}

// ---------------- per-(layer,b,co) proj-weighted tap sums S0,S1,S2 ----------------
__global__ void pc_kernel(const float* __restrict__ proj,
                          const float* __restrict__ conv_w,
                          float* __restrict__ pc) {
  __shared__ float pv[64];
  int layer = blockIdx.x, b = blockIdx.y;
  int tid = threadIdx.x;  // 128
  if (tid < 64) pv[tid] = proj[(layer * 4 + b) * 64 + tid];
  __syncthreads();
  int co = tid;
  const float* w = conv_w + (layer * 128 + co) * 192;
  float s0 = 0.0f, s1 = 0.0f, s2 = 0.0f;
  for (int ci = 0; ci < 64; ++ci) {
    float p = pv[ci];
    s0 += p * w[ci * 3 + 0];
    s1 += p * w[ci * 3 + 1];
    s2 += p * w[ci * 3 + 2];
  }
  float* o = pc + ((layer * 4 + b) * 128 + co) * 3;
  o[0] = s0; o[1] = s1; o[2] = s2;
}

// ---------------- zero the pad margins of x (ws is poisoned every call) ---------
__global__ void padzero_kernel(float* __restrict__ x) {
  int row = blockIdx.x;  // 256 rows = B*C
  float* base = x + (size_t)row * XS * 4;
  for (int i = threadIdx.x; i < XPAD; i += 256) {
    *(float4*)&base[i * 4] = float4{0.f, 0.f, 0.f, 0.f};
    *(float4*)&base[(XPAD + LL + i) * 4] = float4{0.f, 0.f, 0.f, 0.f};
  }
}

// ---------------- Poisson encode + input conv + LIF -> x [B][C][XS][4] ---------
__global__ void encode_lif_kernel(const float* __restrict__ audio,
                                  const float* __restrict__ W_in,
                                  const float* __restrict__ b_in,
                                  float* __restrict__ x) {
  int tid = threadIdx.x;
  int lq = tid & 63, grp = tid >> 6;
  int l = blockIdx.x * 64 + lq;
  int b = blockIdx.y;
  float a = audio[b * LL + l];
  unsigned p0 = (unsigned)(b * LL + l);  // t=0 (o0), t=2 (o1)
  unsigned p1 = 16384u + p0;             // t=1 (o0), t=3 (o1)
  unsigned o00, o01, o10, o11;
  threefry2x32(p0, p0 + 32768u, o00, o01);
  threefry2x32(p1, p1 + 32768u, o10, o11);
  float sp[4];
  sp[0] = (u01(o00) < a) ? 1.0f : 0.0f;
  sp[1] = (u01(o10) < a) ? 1.0f : 0.0f;
  sp[2] = (u01(o01) < a) ? 1.0f : 0.0f;
  sp[3] = (u01(o11) < a) ? 1.0f : 0.0f;
  for (int j = 0; j < 16; ++j) {
    int c = grp * 16 + j;
    float w = W_in[c], bb = b_in[c];
    float v = 0.0f;
    float4 o;
    float* op = (float*)&o;
#pragma unroll
    for (int t = 0; t < 4; ++t) op[t] = lif_step(v, w * sp[t] + bb);
    *(float4*)&x[(size_t)((b * 64 + c) * XS + XPAD + l) * 4] = o;
  }
}

// ---------------- dilated conv + LIF + gate -> y [B][64][LL][4] ----------------
// grid (16, 16, 4): l-tile 256, co-group g (16 x (4 gate + 4 filt)), b.
// block 256. Thread: 1 l, 4 t, 4 gate + 4 filt co.
// KEY CHANGE vs R1/R3: weights are register-prefetched 1 ci AHEAD (double
// buffer), same as x. Previous variants loaded weights inside compute()
// (load->use distance ~0 -> every (ci,k) ate ~120-200cyc LDS/L1 latency vs
// 64cyc of FMA; VALUBusy stuck ~54%, identical at 2 or 4 waves/SIMD).
// Now per-ci compute burst = 192 cyc >= load latency -> steady-state stalls
// covered. Weights from LDS stage (6 KB). Accumulation order (ci asc, k asc)
// unchanged -> bit-exact.
template <int DIL>
__global__ __launch_bounds__(256) void layer_conv_kernel(
    const float* __restrict__ x, const float* __restrict__ wT,
    const float* __restrict__ conv_b, const float* __restrict__ pc,
    float* __restrict__ y, int layer) {
  __shared__ float w_lds[192 * 8];  // [ci*3+k][col8]: col0-3 gate, col4-7 filt
  int tid = threadIdx.x;
  int g = blockIdx.y;   // 0..15
  int b = blockIdx.z;
  int l = blockIdx.x * 256 + tid;
  const float* wbase = wT + (size_t)(layer * 16 + g) * 1536;

  for (int idx = tid; idx < 1536; idx += 256) w_lds[idx] = wbase[idx];
  __syncthreads();

  const float* px = x + (size_t)(b * 64 * XS + XPAD + l) * 4;  // ci=0 row

  v2f ag[8], af[8];  // [t4][pair2]
#pragma unroll
  for (int q = 0; q < 8; ++q) {
    ag[q] = (v2f)(0.0f);
    af[q] = (v2f)(0.0f);
  }

  float4 xa[3], xb[3];          // [k] = 4 t values
  float4 wgA[3], wfA[3];        // weights ci-even buffer
  float4 wgB[3], wfB[3];        // weights ci-odd buffer
  auto loadx = [&](float4* dst) {
    dst[0] = *(const float4*)(px - (size_t)DIL * 4);
    dst[1] = *(const float4*)px;
    dst[2] = *(const float4*)(px + (size_t)DIL * 4);
    px += (size_t)XS * 4;
  };
  auto loadw = [&](int ci, float4* wg, float4* wf) {
#pragma unroll
    for (int k = 0; k < 3; ++k) {
      wg[k] = *(const float4*)&w_lds[(ci * 3 + k) * 8];
      wf[k] = *(const float4*)&w_lds[(ci * 3 + k) * 8 + 4];
    }
  };
  auto compute = [&](const float4* wg, const float4* wf, const float4* xv) {
#pragma unroll
    for (int k = 0; k < 3; ++k) {
      v2f g0, g1, f0, f1;
      g0.x = wg[k].x; g0.y = wg[k].y; g1.x = wg[k].z; g1.y = wg[k].w;
      f0.x = wf[k].x; f0.y = wf[k].y; f1.x = wf[k].z; f1.y = wf[k].w;
      const float* xk = (const float*)&xv[k];
#pragma unroll
      for (int t = 0; t < 4; ++t) {
        float xq = xk[t];
        v2f x2;
        x2.x = xq; x2.y = xq;
        ag[t * 2 + 0] += g0 * x2;
        ag[t * 2 + 1] += g1 * x2;
        af[t * 2 + 0] += f0 * x2;
        af[t * 2 + 1] += f1 * x2;
      }
    }
  };

  loadx(xa);
  loadw(0, wgA, wfA);
  for (int ci = 0; ci < 64; ci += 2) {
    loadx(xb);
    loadw(ci + 1, wgB, wfB);
    compute(wgA, wfA, xa);
    if (ci + 2 < 64) {
      loadx(xa);
      loadw(ci + 2, wgA, wfA);
    }
    compute(wgB, wfB, xb);
  }

  const float SIG1 = 0.73105857863000489f;   // sigmoid(1) fp32
  const float TANH1 = 0.76159415595576486f;  // tanh(1) fp32
  bool lb = (l < DIL), rb = (l >= LL - DIL);
#pragma unroll
  for (int j = 0; j < 4; ++j) {
    int cog = g * 4 + j;
    int cof = 64 + g * 4 + j;
    const float* pg = pc + ((layer * 4 + b) * 128 + cog) * 3;
    const float* pf = pc + ((layer * 4 + b) * 128 + cof) * 3;
    float S0g = pg[0], S1g = pg[1], S2g = pg[2];
    float S0f = pf[0], S1f = pf[1], S2f = pf[2];
    float bg = conv_b[layer * 128 + cog] + S0g + S1g + S2g;
    float bf = conv_b[layer * 128 + cof] + S0f + S1f + S2f;
    bg -= (lb ? S0g : 0.0f) + (rb ? S2g : 0.0f);
    bf -= (lb ? S0f : 0.0f) + (rb ? S2f : 0.0f);
    float vg = 0.0f, vf = 0.0f;
    float4 o;
    float* op = (float*)&o;
#pragma unroll
    for (int t = 0; t < 4; ++t) {
      float av = ag[t * 2 + (j >> 1)][j & 1];
      float fv = af[t * 2 + (j >> 1)][j & 1];
      float sg = lif_step(vg, av + bg);
      float sf = lif_step(vf, fv + bf);
      float gv = (sg != 0.0f) ? SIG1 : 0.5f;
      float tv = (sf != 0.0f) ? TANH1 : 0.0f;
      op[t] = gv * tv;
    }
    *(float4*)&y[(size_t)((b * 64 + cog) * LL + l) * 4] = o;
  }
}

// ---------------- 1x1 skip / res convs ----------------
// grid (64, 2, 4): l-tile 64, cv (0=skip,1=res), b. block 256.
// Thread: 8 c x 2 l x 4 t register tile (32 v2f acc, t-paired pk_fma).
// Per cp: 2 w float4 + 2 y float4, prefetched 1 cp ahead. Sequential cp
// order = same summation order. No LDS. (R0 version — proven best.)
__global__ __launch_bounds__(256) void skip_res_kernel(
    const float* __restrict__ y, const float* __restrict__ skipT,
    const float* __restrict__ resT, const float* __restrict__ skip_b,
    const float* __restrict__ res_b, float* __restrict__ tskip,
    float* __restrict__ x, int layer) {
  int tid = threadIdx.x;
  int lg = tid & 31;   // 32 l-groups of 2
  int cg = tid >> 5;   // 8 c-groups of 8
  int cv = blockIdx.y;
  int b = blockIdx.z;
  int l0 = blockIdx.x * 64 + lg * 2;
  int c0 = cg * 8;

  const float* wsrc = (cv ? resT : skipT) + layer * 4096 + c0;  // [cp][c]
  const float* yb = y + (size_t)(b * 64 * LL + l0) * 4;

  v2f acc[32];  // [c8][l2][t-pair2]
#pragma unroll
  for (int q = 0; q < 32; ++q) acc[q] = (v2f)(0.0f);

  float4 w0a = *(const float4*)&wsrc[0];
  float4 w1a = *(const float4*)&wsrc[4];
  float4 y0a = *(const float4*)yb;             // l0, t0..3
  float4 y1a = *(const float4*)(yb + 4);       // l0+1, t0..3

  for (int cp = 0; cp < 64; ++cp) {
    int cpn = (cp < 63) ? cp + 1 : 63;
    float4 w0b = *(const float4*)&wsrc[cpn * 64];
    float4 w1b = *(const float4*)&wsrc[cpn * 64 + 4];
    float4 y0b = *(const float4*)(yb + (size_t)cpn * LL * 4);
    float4 y1b = *(const float4*)(yb + (size_t)cpn * LL * 4 + 4);

    float wv[8] = {w0a.x, w0a.y, w0a.z, w0a.w, w1a.x, w1a.y, w1a.z, w1a.w};
    const v2f* yp0 = (const v2f*)&y0a;  // t01, t23
    const v2f* yp1 = (const v2f*)&y1a;
#pragma unroll
    for (int i = 0; i < 8; ++i) {
      v2f w2;
      w2.x = wv[i]; w2.y = wv[i];
      acc[i * 4 + 0] += w2 * yp0[0];
      acc[i * 4 + 1] += w2 * yp0[1];
      acc[i * 4 + 2] += w2 * yp1[0];
      acc[i * 4 + 3] += w2 * yp1[1];
    }
    w0a = w0b; w1a = w1b; y0a = y0b; y1a = y1b;
  }

  const float* bsrc = (cv ? res_b : skip_b) + layer * 64 + c0;
#pragma unroll
  for (int i = 0; i < 8; ++i) {
    float bb = bsrc[i];
    float r[8];  // [l2][t4]
#pragma unroll
    for (int q = 0; q < 4; ++q) {
      r[q * 2 + 0] = acc[i * 4 + q][0] + bb;
      r[q * 2 + 1] = acc[i * 4 + q][1] + bb;
    }
    // r[0..3] = l0 t0..3 (acc pairs 0,1); r[4..7] = l0+1 t0..3 (pairs 2,3)
    if (cv == 0) {
      size_t idx = (size_t)((b * 64 + c0 + i) * LL + l0) * 4;
      float4 o0, o1;
      if (layer == 0) {
        o0 = float4{0.f, 0.f, 0.f, 0.f};
        o1 = o0;
      } else {
        o0 = *(const float4*)&tskip[idx];
        o1 = *(const float4*)&tskip[idx + 4];
      }
      o0.x += r[0]; o0.y += r[1]; o0.z += r[2]; o0.w += r[3];
      o1.x += r[4]; o1.y += r[5]; o1.z += r[6]; o1.w += r[7];
      *(float4*)&tskip[idx] = o0;
      *(float4*)&tskip[idx + 4] = o1;
    } else {
      size_t idx = (size_t)((b * 64 + c0 + i) * XS + XPAD + l0) * 4;
      float4 o0 = *(const float4*)&x[idx];
      float4 o1 = *(const float4*)&x[idx + 4];
      o0.x += r[0]; o0.y += r[1]; o0.z += r[2]; o0.w += r[3];
      o1.x += r[4]; o1.y += r[5]; o1.z += r[6]; o1.w += r[7];
      *(float4*)&x[idx] = o0;
      *(float4*)&x[idx + 4] = o1;
    }
  }
}

// ---------------- output conv + LIF + sum over T ----------------
__global__ void out_kernel(const float* __restrict__ tskip,
                           const float* __restrict__ W_out,
                           const float* __restrict__ b_out,
                           float* __restrict__ out) {
  __shared__ float red[4][4][64];  // [grp][t][lq]
  int tid = threadIdx.x;
  int lq = tid & 63, grp = tid >> 6;
  int l = blockIdx.x * 64 + lq;
  int b = blockIdx.y;
  float acc[4] = {0.0f, 0.0f, 0.0f, 0.0f};
  for (int j = 0; j < 16; ++j) {
    int c = grp * 16 + j;
    float w = W_out[c];
    float4 sv = *(const float4*)&tskip[(size_t)((b * 64 + c) * LL + l) * 4];
    acc[0] += fmaxf(sv.x, 0.0f) * w;
    acc[1] += fmaxf(sv.y, 0.0f) * w;
    acc[2] += fmaxf(sv.z, 0.0f) * w;
    acc[3] += fmaxf(sv.w, 0.0f) * w;
  }
#pragma unroll
  for (int t = 0; t < 4; ++t) red[grp][t][lq] = acc[t];
  __syncthreads();
  if (grp == 0) {
    float bo = b_out[0];
    float v = 0.0f, s = 0.0f;
#pragma unroll
    for (int t = 0; t < 4; ++t) {
      float a = red[0][t][lq] + red[1][t][lq] + red[2][t][lq] + red[3][t][lq] + bo;
      s += lif_step(v, a);
    }
    out[b * LL + l] = s;
  }
}

extern "C" void kernel_launch(void* const* d_in, const int* in_sizes, int n_in,
                              void* d_out, int out_size, void* d_ws, size_t ws_size,
                              hipStream_t stream) {
  const float* audio   = (const float*)d_in[0];
  const int*   dstep   = (const int*)d_in[1];
  const float* W_in    = (const float*)d_in[2];
  const float* b_in    = (const float*)d_in[3];
  const float* demb_w1 = (const float*)d_in[4];
  const float* demb_b1 = (const float*)d_in[5];
  const float* demb_w2 = (const float*)d_in[6];
  const float* demb_b2 = (const float*)d_in[7];
  const float* dproj_w = (const float*)d_in[8];
  const float* dproj_b = (const float*)d_in[9];
  const float* conv_w  = (const float*)d_in[10];
  const float* conv_b  = (const float*)d_in[11];
  const float* skip_w  = (const float*)d_in[12];
  const float* skip_b  = (const float*)d_in[13];
  const float* res_w   = (const float*)d_in[14];
  const float* res_b   = (const float*)d_in[15];
  const float* W_out   = (const float*)d_in[16];
  const float* b_out   = (const float*)d_in[17];
  float* out = (float*)d_out;
  float* ws = (float*)d_ws;

  float* proj  = ws;                   // 2560
  float* skipT = proj + 2560;          // 40960
  float* resT  = skipT + 40960;        // 40960
  float* pc    = resT + 40960;         // 15360
  float* wT    = pc + 15360;           // 10*16*64*24 = 245760
  float* x     = wT + 245760;          // 4*64*5120*4 = 5242880
  float* y     = x + 5242880;          // 4*64*4096*4 = 4194304
  float* tskip = y + 4194304;          // 4194304

  prep_kernel<<<10, 256, 0, stream>>>(skip_w, res_w, conv_w, skipT, resT, wT);
  proj_kernel<<<10, 256, 0, stream>>>(dstep, demb_w1, demb_b1, demb_w2, demb_b2,
                                      dproj_w, dproj_b, proj);
  pc_kernel<<<dim3(10, 4), 128, 0, stream>>>(proj, conv_w, pc);
  padzero_kernel<<<256, 256, 0, stream>>>(x);
  encode_lif_kernel<<<dim3(64, 4), 256, 0, stream>>>(audio, W_in, b_in, x);

  for (int i = 0; i < NLAYERS; ++i) {
    dim3 gc(16, 16, 4);
    switch (i) {
      case 0: layer_conv_kernel<1><<<gc, 256, 0, stream>>>(x, wT, conv_b, pc, y, i); break;
      case 1: layer_conv_kernel<2><<<gc, 256, 0, stream>>>(x, wT, conv_b, pc, y, i); break;
      case 2: layer_conv_kernel<4><<<gc, 256, 0, stream>>>(x, wT, conv_b, pc, y, i); break;
      case 3: layer_conv_kernel<8><<<gc, 256, 0, stream>>>(x, wT, conv_b, pc, y, i); break;
      case 4: layer_conv_kernel<16><<<gc, 256, 0, stream>>>(x, wT, conv_b, pc, y, i); break;
      case 5: layer_conv_kernel<32><<<gc, 256, 0, stream>>>(x, wT, conv_b, pc, y, i); break;
      case 6: layer_conv_kernel<64><<<gc, 256, 0, stream>>>(x, wT, conv_b, pc, y, i); break;
      case 7: layer_conv_kernel<128><<<gc, 256, 0, stream>>>(x, wT, conv_b, pc, y, i); break;
      case 8: layer_conv_kernel<256><<<gc, 256, 0, stream>>>(x, wT, conv_b, pc, y, i); break;
      case 9: layer_conv_kernel<512><<<gc, 256, 0, stream>>>(x, wT, conv_b, pc, y, i); break;
    }
    skip_res_kernel<<<dim3(64, 2, 4), 256, 0, stream>>>(y, skipT, resT, skip_b,
                                                        res_b, tskip, x, i);
  }
  out_kernel<<<dim3(64, 4), 256, 0, stream>>>(tskip, W_out, b_out, out);
}

// Round 6
// 809.085 us; speedup vs baseline: 1.2967x; 1.1013x over previous
//
#include <hip/hip_runtime.h>

#define LL 4096
#define NB 4
#define NC 64
#define NT 4
#define NLAYERS 10
#define XS 5120   // padded x row stride (in l units; x is [B][C][XS][4])
#define XPAD 512  // left/right zero pad (>= max dilation)

typedef float v2f __attribute__((ext_vector_type(2)));

// Constant-address-space cast (composable_kernel pattern): forces s_load for
// wave-uniform weight reads -> weights live in SGPRs, FMA becomes
// v_fmac_f32 acc, s_w, v_x with zero packing overhead.
typedef __attribute__((address_space(4))) const float cfloat;
__device__ __forceinline__ cfloat* to_constant(const float* p) {
  return (cfloat*)(unsigned long long)p;
}

// ---------------- Threefry-2x32, key = (0, 42), 20 rounds ----------------
__device__ __forceinline__ void threefry2x32(unsigned x0, unsigned x1,
                                             unsigned& o0, unsigned& o1) {
  const unsigned ks0 = 0u, ks1 = 42u;
  const unsigned ks2 = 0x1BD11BDAu ^ ks0 ^ ks1;
  const unsigned ks[3] = {ks0, ks1, ks2};
  const unsigned r0[4] = {13u, 15u, 26u, 6u};
  const unsigned r1[4] = {17u, 29u, 16u, 24u};
  x0 += ks0; x1 += ks1;
#pragma unroll
  for (int g = 0; g < 5; ++g) {
    const unsigned* rr = (g & 1) ? r1 : r0;
#pragma unroll
    for (int j = 0; j < 4; ++j) {
      x0 += x1;
      unsigned r = rr[j];
      x1 = (x1 << r) | (x1 >> (32u - r));
      x1 ^= x0;
    }
    x0 += ks[(g + 1) % 3];
    x1 += ks[(g + 2) % 3] + (unsigned)(g + 1);
  }
  o0 = x0; o1 = x1;
}

__device__ __forceinline__ float u01(unsigned bits) {
  return __uint_as_float((bits >> 9) | 0x3f800000u) - 1.0f;
}

// LIF step: v = v + (x - v)/1.2 ; spike = v>=0.5 ; v *= (1-spike)
__device__ __forceinline__ float lif_step(float& v, float xt) {
  v = v + (xt - v) / 1.2f;
  float s = (v >= 0.5f) ? 1.0f : 0.0f;
  v = v * (1.0f - s);
  return s;
}

// ---------------- prep: transpose skip/res 1x1 + build wT ----------------
// skipT/resT: [i][c'][c]. wT: [i][g16][ci][k][col8], col<4 gate co=g*4+col,
// col>=4 filt co=64+g*4+col-4.
__global__ void prep_kernel(const float* __restrict__ skip_w,
                            const float* __restrict__ res_w,
                            const float* __restrict__ conv_w,
                            float* __restrict__ skipT,
                            float* __restrict__ resT,
                            float* __restrict__ wT) {
  int i = blockIdx.x;
  for (int idx = threadIdx.x; idx < 4096; idx += 256) {
    int c = idx >> 6, cp = idx & 63;
    skipT[i * 4096 + cp * 64 + c] = skip_w[i * 4096 + c * 64 + cp];
    resT[i * 4096 + cp * 64 + c] = res_w[i * 4096 + c * 64 + cp];
  }
  for (int idx = threadIdx.x; idx < 16 * 64 * 3 * 8; idx += 256) {
    int col = idx & 7;
    int r = idx >> 3;
    int k = r % 3; r /= 3;
    int ci = r % 64;
    int g = r / 64;  // 0..15
    int co = (col < 4) ? (g * 4 + col) : (64 + g * 4 + (col - 4));
    wT[i * 24576 + idx] = conv_w[(i * 128 + co) * 192 + ci * 3 + k];
  }
}

// ---------------- diffusion-step embedding -> proj[i][b][c] ----------------
__global__ void proj_kernel(const int* __restrict__ dstep,
                            const float* __restrict__ w1, const float* __restrict__ b1,
                            const float* __restrict__ w2, const float* __restrict__ b2,
                            const float* __restrict__ pw, const float* __restrict__ pb,
                            float* __restrict__ proj) {
  __shared__ float e1[NB][NC];
  __shared__ float e2[NB][NC];
  int i = blockIdx.x;
  int tid = threadIdx.x;
  int b = tid >> 6, c = tid & 63;
  float d = (float)dstep[b];
  float v = d * w1[i * 64 + c] + b1[i * 64 + c];
  v = v / (1.0f + expf(-v));  // silu
  e1[b][c] = v;
  __syncthreads();
  float a = b2[i * 64 + c];
  for (int cp = 0; cp < 64; ++cp) a += e1[b][cp] * w2[(i * 64 + c) * 64 + cp];
  e2[b][c] = a;
  __syncthreads();
  float p = pb[i * 64 + c];
  for (int cp = 0; cp < 64; ++cp) p += e2[b][cp] * pw[(i * 64 + c) * 64 + cp];
  proj[(i * 4 + b) * 64 + c] = p;
}

// ---------------- per-(layer,b,co) proj-weighted tap sums S0,S1,S2 ----------------
__global__ void pc_kernel(const float* __restrict__ proj,
                          const float* __restrict__ conv_w,
                          float* __restrict__ pc) {
  __shared__ float pv[64];
  int layer = blockIdx.x, b = blockIdx.y;
  int tid = threadIdx.x;  // 128
  if (tid < 64) pv[tid] = proj[(layer * 4 + b) * 64 + tid];
  __syncthreads();
  int co = tid;
  const float* w = conv_w + (layer * 128 + co) * 192;
  float s0 = 0.0f, s1 = 0.0f, s2 = 0.0f;
  for (int ci = 0; ci < 64; ++ci) {
    float p = pv[ci];
    s0 += p * w[ci * 3 + 0];
    s1 += p * w[ci * 3 + 1];
    s2 += p * w[ci * 3 + 2];
  }
  float* o = pc + ((layer * 4 + b) * 128 + co) * 3;
  o[0] = s0; o[1] = s1; o[2] = s2;
}

// ---------------- zero the pad margins of x (ws is poisoned every call) ---------
__global__ void padzero_kernel(float* __restrict__ x) {
  int row = blockIdx.x;  // 256 rows = B*C
  float* base = x + (size_t)row * XS * 4;
  for (int i = threadIdx.x; i < XPAD; i += 256) {
    *(float4*)&base[i * 4] = float4{0.f, 0.f, 0.f, 0.f};
    *(float4*)&base[(XPAD + LL + i) * 4] = float4{0.f, 0.f, 0.f, 0.f};
  }
}

// ---------------- Poisson encode + input conv + LIF -> x [B][C][XS][4] ---------
__global__ void encode_lif_kernel(const float* __restrict__ audio,
                                  const float* __restrict__ W_in,
                                  const float* __restrict__ b_in,
                                  float* __restrict__ x) {
  int tid = threadIdx.x;
  int lq = tid & 63, grp = tid >> 6;
  int l = blockIdx.x * 64 + lq;
  int b = blockIdx.y;
  float a = audio[b * LL + l];
  unsigned p0 = (unsigned)(b * LL + l);  // t=0 (o0), t=2 (o1)
  unsigned p1 = 16384u + p0;             // t=1 (o0), t=3 (o1)
  unsigned o00, o01, o10, o11;
  threefry2x32(p0, p0 + 32768u, o00, o01);
  threefry2x32(p1, p1 + 32768u, o10, o11);
  float sp[4];
  sp[0] = (u01(o00) < a) ? 1.0f : 0.0f;
  sp[1] = (u01(o10) < a) ? 1.0f : 0.0f;
  sp[2] = (u01(o01) < a) ? 1.0f : 0.0f;
  sp[3] = (u01(o11) < a) ? 1.0f : 0.0f;
  for (int j = 0; j < 16; ++j) {
    int c = grp * 16 + j;
    float w = W_in[c], bb = b_in[c];
    float v = 0.0f;
    float4 o;
    float* op = (float*)&o;
#pragma unroll
    for (int t = 0; t < 4; ++t) op[t] = lif_step(v, w * sp[t] + bb);
    *(float4*)&x[(size_t)((b * 64 + c) * XS + XPAD + l) * 4] = o;
  }
}

// ---------------- dilated conv + LIF + gate -> y [B][64][LL][4] ----------------
// grid (16, 16, 4): l-tile 256, co-group g (16 x (4 gate + 4 filt)), b.
// block 256. Thread: 1 l, 4 t, 8 co; acc[8][4] scalar f32.
// KEY CHANGE vs R5 (which proved the stall model wrong): the MAC is now
// acc[co][t] += w[co] * x[t] with w WAVE-UNIFORM and loaded via the
// CONSTANT ADDRESS SPACE (s_load -> SGPR). Every MAC is a single
// v_fmac_f32 acc, s_w, v_x: no v2f splat movs, no float4->v2f unpacks,
// no LDS, no ds_read. R5's VALU issue was ~2/3 packing overhead
// (32us issue vs 10us FMA content); this mix is 6144 fmac + ~500 misc
// ~ 21us pure issue at 4 waves/SIMD. Weights A/B-prefetched 1 ci ahead
// on the scalar pipe; x keeps the proven float4 prefetch.
// Accumulation order (ci asc, k asc) unchanged -> bit-exact.
template <int DIL>
__global__ __launch_bounds__(256) void layer_conv_kernel(
    const float* __restrict__ x, const float* __restrict__ wT,
    const float* __restrict__ conv_b, const float* __restrict__ pc,
    float* __restrict__ y, int layer) {
  int tid = threadIdx.x;
  int g = blockIdx.y;   // 0..15
  int b = blockIdx.z;
  int l = blockIdx.x * 256 + tid;
  cfloat* cw = to_constant(wT + (size_t)(layer * 16 + g) * 1536);

  const float* px = x + (size_t)(b * 64 * XS + XPAD + l) * 4;  // ci=0 row

  float acc[8][4];  // [col][t]; col 0-3 gate, 4-7 filt
#pragma unroll
  for (int j = 0; j < 8; ++j)
#pragma unroll
    for (int t = 0; t < 4; ++t) acc[j][t] = 0.0f;

  float4 xa[3], xb[3];      // [k] = 4 t values
  float wA[3][8], wB[3][8]; // [k][col] wave-uniform -> SGPRs

  auto loadx = [&](float4* dst) {
    dst[0] = *(const float4*)(px - (size_t)DIL * 4);
    dst[1] = *(const float4*)px;
    dst[2] = *(const float4*)(px + (size_t)DIL * 4);
    px += (size_t)XS * 4;
  };
  auto loadw = [&](int ci, float (*w)[8]) {
#pragma unroll
    for (int k = 0; k < 3; ++k)
#pragma unroll
      for (int j = 0; j < 8; ++j)
        w[k][j] = cw[(ci * 3 + k) * 8 + j];  // s_load (merged to dwordx4/x8)
  };
  auto compute = [&](const float (*w)[8], const float4* xv) {
#pragma unroll
    for (int k = 0; k < 3; ++k) {
      const float* xk = (const float*)&xv[k];
#pragma unroll
      for (int t = 0; t < 4; ++t) {
        float xq = xk[t];
#pragma unroll
        for (int j = 0; j < 8; ++j)
          acc[j][t] += w[k][j] * xq;  // v_fmac_f32 acc, s, v
      }
    }
  };

  loadx(xa);
  loadw(0, wA);
  for (int ci = 0; ci < 64; ci += 2) {
    loadx(xb);
    loadw(ci + 1, wB);
    compute(wA, xa);
    if (ci + 2 < 64) {
      loadx(xa);
      loadw(ci + 2, wA);
    }
    compute(wB, xb);
  }

  const float SIG1 = 0.73105857863000489f;   // sigmoid(1) fp32
  const float TANH1 = 0.76159415595576486f;  // tanh(1) fp32
  bool lb = (l < DIL), rb = (l >= LL - DIL);
#pragma unroll
  for (int j = 0; j < 4; ++j) {
    int cog = g * 4 + j;
    int cof = 64 + g * 4 + j;
    const float* pg = pc + ((layer * 4 + b) * 128 + cog) * 3;
    const float* pf = pc + ((layer * 4 + b) * 128 + cof) * 3;
    float S0g = pg[0], S1g = pg[1], S2g = pg[2];
    float S0f = pf[0], S1f = pf[1], S2f = pf[2];
    float bg = conv_b[layer * 128 + cog] + S0g + S1g + S2g;
    float bf = conv_b[layer * 128 + cof] + S0f + S1f + S2f;
    bg -= (lb ? S0g : 0.0f) + (rb ? S2g : 0.0f);
    bf -= (lb ? S0f : 0.0f) + (rb ? S2f : 0.0f);
    float vg = 0.0f, vf = 0.0f;
    float4 o;
    float* op = (float*)&o;
#pragma unroll
    for (int t = 0; t < 4; ++t) {
      float av = acc[j][t];
      float fv = acc[j + 4][t];
      float sg = lif_step(vg, av + bg);
      float sf = lif_step(vf, fv + bf);
      float gv = (sg != 0.0f) ? SIG1 : 0.5f;
      float tv = (sf != 0.0f) ? TANH1 : 0.0f;
      op[t] = gv * tv;
    }
    *(float4*)&y[(size_t)((b * 64 + cog) * LL + l) * 4] = o;
  }
}

// ---------------- 1x1 skip / res convs ----------------
// grid (64, 2, 4): l-tile 64, cv (0=skip,1=res), b. block 256.
// Thread: 8 c x 2 l x 4 t register tile (32 v2f acc, t-paired pk_fma).
// Per cp: 2 w float4 + 2 y float4, prefetched 1 cp ahead. Sequential cp
// order = same summation order. No LDS. (R0 version — proven best.)
__global__ __launch_bounds__(256) void skip_res_kernel(
    const float* __restrict__ y, const float* __restrict__ skipT,
    const float* __restrict__ resT, const float* __restrict__ skip_b,
    const float* __restrict__ res_b, float* __restrict__ tskip,
    float* __restrict__ x, int layer) {
  int tid = threadIdx.x;
  int lg = tid & 31;   // 32 l-groups of 2
  int cg = tid >> 5;   // 8 c-groups of 8
  int cv = blockIdx.y;
  int b = blockIdx.z;
  int l0 = blockIdx.x * 64 + lg * 2;
  int c0 = cg * 8;

  const float* wsrc = (cv ? resT : skipT) + layer * 4096 + c0;  // [cp][c]
  const float* yb = y + (size_t)(b * 64 * LL + l0) * 4;

  v2f acc[32];  // [c8][l2][t-pair2]
#pragma unroll
  for (int q = 0; q < 32; ++q) acc[q] = (v2f)(0.0f);

  float4 w0a = *(const float4*)&wsrc[0];
  float4 w1a = *(const float4*)&wsrc[4];
  float4 y0a = *(const float4*)yb;             // l0, t0..3
  float4 y1a = *(const float4*)(yb + 4);       // l0+1, t0..3

  for (int cp = 0; cp < 64; ++cp) {
    int cpn = (cp < 63) ? cp + 1 : 63;
    float4 w0b = *(const float4*)&wsrc[cpn * 64];
    float4 w1b = *(const float4*)&wsrc[cpn * 64 + 4];
    float4 y0b = *(const float4*)(yb + (size_t)cpn * LL * 4);
    float4 y1b = *(const float4*)(yb + (size_t)cpn * LL * 4 + 4);

    float wv[8] = {w0a.x, w0a.y, w0a.z, w0a.w, w1a.x, w1a.y, w1a.z, w1a.w};
    const v2f* yp0 = (const v2f*)&y0a;  // t01, t23
    const v2f* yp1 = (const v2f*)&y1a;
#pragma unroll
    for (int i = 0; i < 8; ++i) {
      v2f w2;
      w2.x = wv[i]; w2.y = wv[i];
      acc[i * 4 + 0] += w2 * yp0[0];
      acc[i * 4 + 1] += w2 * yp0[1];
      acc[i * 4 + 2] += w2 * yp1[0];
      acc[i * 4 + 3] += w2 * yp1[1];
    }
    w0a = w0b; w1a = w1b; y0a = y0b; y1a = y1b;
  }

  const float* bsrc = (cv ? res_b : skip_b) + layer * 64 + c0;
#pragma unroll
  for (int i = 0; i < 8; ++i) {
    float bb = bsrc[i];
    float r[8];  // [l2][t4]
#pragma unroll
    for (int q = 0; q < 4; ++q) {
      r[q * 2 + 0] = acc[i * 4 + q][0] + bb;
      r[q * 2 + 1] = acc[i * 4 + q][1] + bb;
    }
    // r[0..3] = l0 t0..3 (acc pairs 0,1); r[4..7] = l0+1 t0..3 (pairs 2,3)
    if (cv == 0) {
      size_t idx = (size_t)((b * 64 + c0 + i) * LL + l0) * 4;
      float4 o0, o1;
      if (layer == 0) {
        o0 = float4{0.f, 0.f, 0.f, 0.f};
        o1 = o0;
      } else {
        o0 = *(const float4*)&tskip[idx];
        o1 = *(const float4*)&tskip[idx + 4];
      }
      o0.x += r[0]; o0.y += r[1]; o0.z += r[2]; o0.w += r[3];
      o1.x += r[4]; o1.y += r[5]; o1.z += r[6]; o1.w += r[7];
      *(float4*)&tskip[idx] = o0;
      *(float4*)&tskip[idx + 4] = o1;
    } else {
      size_t idx = (size_t)((b * 64 + c0 + i) * XS + XPAD + l0) * 4;
      float4 o0 = *(const float4*)&x[idx];
      float4 o1 = *(const float4*)&x[idx + 4];
      o0.x += r[0]; o0.y += r[1]; o0.z += r[2]; o0.w += r[3];
      o1.x += r[4]; o1.y += r[5]; o1.z += r[6]; o1.w += r[7];
      *(float4*)&x[idx] = o0;
      *(float4*)&x[idx + 4] = o1;
    }
  }
}

// ---------------- output conv + LIF + sum over T ----------------
__global__ void out_kernel(const float* __restrict__ tskip,
                           const float* __restrict__ W_out,
                           const float* __restrict__ b_out,
                           float* __restrict__ out) {
  __shared__ float red[4][4][64];  // [grp][t][lq]
  int tid = threadIdx.x;
  int lq = tid & 63, grp = tid >> 6;
  int l = blockIdx.x * 64 + lq;
  int b = blockIdx.y;
  float acc[4] = {0.0f, 0.0f, 0.0f, 0.0f};
  for (int j = 0; j < 16; ++j) {
    int c = grp * 16 + j;
    float w = W_out[c];
    float4 sv = *(const float4*)&tskip[(size_t)((b * 64 + c) * LL + l) * 4];
    acc[0] += fmaxf(sv.x, 0.0f) * w;
    acc[1] += fmaxf(sv.y, 0.0f) * w;
    acc[2] += fmaxf(sv.z, 0.0f) * w;
    acc[3] += fmaxf(sv.w, 0.0f) * w;
  }
#pragma unroll
  for (int t = 0; t < 4; ++t) red[grp][t][lq] = acc[t];
  __syncthreads();
  if (grp == 0) {
    float bo = b_out[0];
    float v = 0.0f, s = 0.0f;
#pragma unroll
    for (int t = 0; t < 4; ++t) {
      float a = red[0][t][lq] + red[1][t][lq] + red[2][t][lq] + red[3][t][lq] + bo;
      s += lif_step(v, a);
    }
    out[b * LL + l] = s;
  }
}

extern "C" void kernel_launch(void* const* d_in, const int* in_sizes, int n_in,
                              void* d_out, int out_size, void* d_ws, size_t ws_size,
                              hipStream_t stream) {
  const float* audio   = (const float*)d_in[0];
  const int*   dstep   = (const int*)d_in[1];
  const float* W_in    = (const float*)d_in[2];
  const float* b_in    = (const float*)d_in[3];
  const float* demb_w1 = (const float*)d_in[4];
  const float* demb_b1 = (const float*)d_in[5];
  const float* demb_w2 = (const float*)d_in[6];
  const float* demb_b2 = (const float*)d_in[7];
  const float* dproj_w = (const float*)d_in[8];
  const float* dproj_b = (const float*)d_in[9];
  const float* conv_w  = (const float*)d_in[10];
  const float* conv_b  = (const float*)d_in[11];
  const float* skip_w  = (const float*)d_in[12];
  const float* skip_b  = (const float*)d_in[13];
  const float* res_w   = (const float*)d_in[14];
  const float* res_b   = (const float*)d_in[15];
  const float* W_out   = (const float*)d_in[16];
  const float* b_out   = (const float*)d_in[17];
  float* out = (float*)d_out;
  float* ws = (float*)d_ws;

  float* proj  = ws;                   // 2560
  float* skipT = proj + 2560;          // 40960
  float* resT  = skipT + 40960;        // 40960
  float* pc    = resT + 40960;         // 15360
  float* wT    = pc + 15360;           // 10*16*64*24 = 245760
  float* x     = wT + 245760;          // 4*64*5120*4 = 5242880
  float* y     = x + 5242880;          // 4*64*4096*4 = 4194304
  float* tskip = y + 4194304;          // 4194304

  prep_kernel<<<10, 256, 0, stream>>>(skip_w, res_w, conv_w, skipT, resT, wT);
  proj_kernel<<<10, 256, 0, stream>>>(dstep, demb_w1, demb_b1, demb_w2, demb_b2,
                                      dproj_w, dproj_b, proj);
  pc_kernel<<<dim3(10, 4), 128, 0, stream>>>(proj, conv_w, pc);
  padzero_kernel<<<256, 256, 0, stream>>>(x);
  encode_lif_kernel<<<dim3(64, 4), 256, 0, stream>>>(audio, W_in, b_in, x);

  for (int i = 0; i < NLAYERS; ++i) {
    dim3 gc(16, 16, 4);
    switch (i) {
      case 0: layer_conv_kernel<1><<<gc, 256, 0, stream>>>(x, wT, conv_b, pc, y, i); break;
      case 1: layer_conv_kernel<2><<<gc, 256, 0, stream>>>(x, wT, conv_b, pc, y, i); break;
      case 2: layer_conv_kernel<4><<<gc, 256, 0, stream>>>(x, wT, conv_b, pc, y, i); break;
      case 3: layer_conv_kernel<8><<<gc, 256, 0, stream>>>(x, wT, conv_b, pc, y, i); break;
      case 4: layer_conv_kernel<16><<<gc, 256, 0, stream>>>(x, wT, conv_b, pc, y, i); break;
      case 5: layer_conv_kernel<32><<<gc, 256, 0, stream>>>(x, wT, conv_b, pc, y, i); break;
      case 6: layer_conv_kernel<64><<<gc, 256, 0, stream>>>(x, wT, conv_b, pc, y, i); break;
      case 7: layer_conv_kernel<128><<<gc, 256, 0, stream>>>(x, wT, conv_b, pc, y, i); break;
      case 8: layer_conv_kernel<256><<<gc, 256, 0, stream>>>(x, wT, conv_b, pc, y, i); break;
      case 9: layer_conv_kernel<512><<<gc, 256, 0, stream>>>(x, wT, conv_b, pc, y, i); break;
    }
    skip_res_kernel<<<dim3(64, 2, 4), 256, 0, stream>>>(y, skipT, resT, skip_b,
                                                        res_b, tskip, x, i);
  }
  out_kernel<<<dim3(64, 4), 256, 0, stream>>>(tskip, W_out, b_out, out);
}